// Round 12
// baseline (99.562 us; speedup 1.0000x reference)
//
#include <hip/hip_runtime.h>

#define NBATCH 32
#define LPATH 256
#define NSEG 255
#define SIGLEN 4680       // 8 + 64 + 512 + 4096
#define PSTR 4688         // partial stride (floats), 8B-aligned
#define INV6 (1.0f/6.0f)
#define INV24 (1.0f/24.0f)

typedef float v2f __attribute__((ext_vector_type(2)));

// Per-signature LDS buffer, exchange-friendly layouts (see R7):
//  T4t2 : [ (c*4+eh)*128 + 2*l + p ]  (lane l=(a<<3)|b owns (a,b,c,2eh+p))
//  T3b  : [ x*68 + y*8 + z ]          T2: [a*8+b]   T1: [a]
struct __align__(16) CBuf {
    float T4t2[64 * 64];
    float T3b[8 * 68];
    float T2[64];
    float T1[8];
};                        // 18848 B; x4 = 75392 B

__device__ __forceinline__ void publish_sig(CBuf& B, const v2f S4v[32],
                                            const float S3[8], float S2, float a1a,
                                            int l, int a, int b) {
    #pragma unroll
    for (int ch = 0; ch < 32; ++ch)
        *(v2f*)&B.T4t2[ch * 128 + 2 * l] = S4v[ch];
    #pragma unroll
    for (int c = 0; c < 8; ++c)
        B.T3b[a * 68 + b * 8 + c] = S3[c];
    B.T2[l] = S2;
    if (b == 0) B.T1[a] = a1a;
}

__device__ __forceinline__ void absorb_sig(const CBuf& B, v2f S4v[32], float S3[8],
                                           float& S2, float& a1a, int l, int a, int b) {
    v2f t1v[4];
    #pragma unroll
    for (int h = 0; h < 4; ++h) t1v[h] = *(const v2f*)&B.T1[2 * h];
    const float t1a = B.T1[a];
    const float t1b = B.T1[b];
    const v2f S2v = S2, a1v = a1a;
    #pragma unroll
    for (int c = 0; c < 8; ++c) {
        const v2f S3cv = S3[c];
        #pragma unroll
        for (int h = 0; h < 4; ++h) {
            const v2f t2v = *(const v2f*)&B.T2[c * 8 + 2 * h];
            const v2f t3v = *(const v2f*)&B.T3b[b * 68 + c * 8 + 2 * h];
            const v2f t4v = *(const v2f*)&B.T4t2[(c * 4 + h) * 128 + 2 * l];
            v2f acc = S4v[c * 4 + h] + t4v;
            acc = __builtin_elementwise_fma(S3cv, t1v[h], acc);
            acc = __builtin_elementwise_fma(S2v, t2v, acc);
            acc = __builtin_elementwise_fma(a1v, t3v, acc);
            S4v[c * 4 + h] = acc;
        }
    }
    #pragma unroll
    for (int c = 0; c < 8; ++c)
        S3[c] += S2 * B.T1[c] + a1a * B.T2[b * 8 + c] + B.T3b[a * 68 + b * 8 + c];
    S2 += a1a * t1b + B.T2[l];
    a1a += t1a;
}

__device__ __forceinline__ void tree3(CBuf* bufs, v2f S4v[32], float S3[8],
                                      float& S2, float& a1a, int w, int l, int a, int b) {
    #pragma unroll
    for (int r = 0; r < 3; ++r) {
        const int stride = 1 << r;
        const int m = (stride << 1) - 1;
        if ((w & m) == stride)
            publish_sig(bufs[w >> (r + 1)], S4v, S3, S2, a1a, l, a, b);
        __syncthreads();
        if ((w & m) == 0)
            absorb_sig(bufs[w >> (r + 1)], S4v, S3, S2, a1a, l, a, b);
        __syncthreads();
    }
}

// 256 blocks = 32 batches x 8 chunks of 32 segments; 512 threads = 8 waves.
// Each block: scan 4 segs/wave -> tree3 -> wave0 stores partial -> fence+atomic.
// Last-arriving block per batch loads the 8 partials (wave k -> partial k),
// reruns tree3, writes the final signature. Fixed combine order => deterministic.
// amdgpu_waves_per_eu(2,2): force the allocator's occupancy target to 2
// waves/SIMD so it uses up to 256 VGPR and does NOT spill S4v (R8/R11 disease).
__global__ __launch_bounds__(512)
__attribute__((amdgpu_waves_per_eu(2, 2)))
void sig_kernel(const float* __restrict__ path,
                float* __restrict__ pbase,
                int* __restrict__ flags,
                float* __restrict__ out) {
    const int blk = blockIdx.x;
    const int n = blk >> 3, cb = blk & 7;
    const int t = threadIdx.x;
    const int w = t >> 6, l = t & 63, a = l >> 3, b = l & 7;

    __shared__ CBuf bufs[4];
    __shared__ float dbuf[256];   // this block's 32 segments x 8
    __shared__ int sh_old;

    const float* prow = path + n * (LPATH * 8);
    if (t < 64) {
        const int i4 = t * 4;
        const int g4 = cb * 256 + i4;
        if (g4 < NSEG * 8) {       // seg <= 254: real increment quad
            const float4 x0 = *(const float4*)&prow[g4];
            const float4 x1 = *(const float4*)&prow[g4 + 8];
            *(float4*)&dbuf[i4] = make_float4(x1.x - x0.x, x1.y - x0.y,
                                              x1.z - x0.z, x1.w - x0.w);
        } else {                   // seg 255: identity pad
            *(float4*)&dbuf[i4] = make_float4(0.f, 0.f, 0.f, 0.f);
        }
    }
    __syncthreads();

    v2f S4v[32];
    float S3[8];
    #pragma unroll
    for (int j = 0; j < 32; ++j) S4v[j] = (v2f)0.f;
    #pragma unroll
    for (int c = 0; c < 8; ++c) S3[c] = 0.f;
    float S2 = 0.f, a1a = 0.f;

    // per-wave / per-lane LDS bases: wave w owns 4 segments = 32 floats
    const float* wbase = &dbuf[w << 5];
    const float* abase = wbase + a;
    const float* bbase = wbase + b;

    // ---- scan 4 segments, fully unrolled ----
    #pragma unroll
    for (int ss = 0; ss < 4; ++ss) {
        const float4 dlo = *(const float4*)&wbase[ss * 8];
        const float4 dhi = *(const float4*)&wbase[ss * 8 + 4];
        const v2f dp[4] = {{dlo.x, dlo.y}, {dlo.z, dlo.w},
                           {dhi.x, dhi.y}, {dhi.z, dhi.w}};
        const float da = abase[ss * 8];
        const float db = bbase[ss * 8];
        const float dab = da * db;
        const float P = dab * INV24 + a1a * db * INV6 + S2 * 0.5f;
        const float Q = dab * INV6  + a1a * db * 0.5f + S2;
        const v2f Pv = P, Qv = Q;
        v2f Kv[4];
        #pragma unroll
        for (int h = 0; h < 4; ++h) {
            v2f S3h = {S3[2 * h], S3[2 * h + 1]};
            Kv[h] = __builtin_elementwise_fma(dp[h], Pv, S3h);
            S3h = __builtin_elementwise_fma(dp[h], Qv, S3h);
            S3[2 * h] = S3h.x; S3[2 * h + 1] = S3h.y;
        }
        #pragma unroll
        for (int c = 0; c < 8; ++c) {
            const float Kc = (c & 1) ? Kv[c >> 1].y : Kv[c >> 1].x;
            const v2f Kcv = Kc;
            #pragma unroll
            for (int h = 0; h < 4; ++h)
                S4v[c * 4 + h] = __builtin_elementwise_fma(dp[h], Kcv, S4v[c * 4 + h]);
        }
        S2 += db * (da * 0.5f + a1a);
        a1a += da;
    }

    // ---- intra-block combine ----
    tree3(bufs, S4v, S3, S2, a1a, w, l, a, b);

    // ---- wave 0 stores the block partial (coalesced pairs, transposed S4) ----
    if (w == 0) {
        float* p = pbase + (size_t)blk * PSTR;
        if (b == 0) p[a] = a1a;
        p[8 + l] = S2;
        #pragma unroll
        for (int c = 0; c < 8; ++c) p[72 + c * 64 + l] = S3[c];
        #pragma unroll
        for (int ch = 0; ch < 32; ++ch)
            *(v2f*)&p[584 + ch * 128 + 2 * l] = S4v[ch];
    }

    // ---- release partial, count arrivals ----
    __threadfence();
    __syncthreads();
    if (t == 0)
        sh_old = __hip_atomic_fetch_add(&flags[n], 1, __ATOMIC_ACQ_REL,
                                        __HIP_MEMORY_SCOPE_AGENT);
    __syncthreads();
    if (sh_old != 7) return;      // not the last block of this batch

    // ---- combiner: load the 8 partials (wave k -> partial k) ----
    __threadfence();
    {
        const float* p = pbase + (size_t)(n * 8 + w) * PSTR;
        a1a = p[a];
        S2 = p[8 + l];
        #pragma unroll
        for (int c = 0; c < 8; ++c) S3[c] = p[72 + c * 64 + l];
        #pragma unroll
        for (int ch = 0; ch < 32; ++ch)
            S4v[ch] = *(const v2f*)&p[584 + ch * 128 + 2 * l];
    }
    __syncthreads();

    tree3(bufs, S4v, S3, S2, a1a, w, l, a, b);

    // ---- wave 0 writes the final signature ----
    if (w == 0) {
        float* o = out + n * SIGLEN;
        if (b == 0) o[a] = a1a;
        o[8 + l] = S2;
        *(float4*)&o[72 + l * 8]     = make_float4(S3[0], S3[1], S3[2], S3[3]);
        *(float4*)&o[72 + l * 8 + 4] = make_float4(S3[4], S3[5], S3[6], S3[7]);
        #pragma unroll
        for (int ch = 0; ch < 32; ++ch)
            *(v2f*)&o[584 + l * 64 + 2 * ch] = S4v[ch];   // (a,b,c,e) order
    }
}

extern "C" void kernel_launch(void* const* d_in, const int* in_sizes, int n_in,
                              void* d_out, int out_size, void* d_ws, size_t ws_size,
                              hipStream_t stream) {
    const float* path = (const float*)d_in[0];
    float* out = (float*)d_out;
    int* flags = (int*)d_ws;                      // 32 ints
    float* pbase = (float*)d_ws + 256;            // partials, 1 KB offset
    hipMemsetAsync(d_ws, 0, NBATCH * sizeof(int), stream);
    sig_kernel<<<NBATCH * 8, 512, 0, stream>>>(path, pbase, flags, out);
}

// Round 13
// 21.418 us; speedup vs baseline: 4.6485x; 4.6485x over previous
//
#include <hip/hip_runtime.h>

#define NBATCH 32
#define LPATH 256
#define NSEG 255
#define SIGLEN 4680       // 8 + 64 + 512 + 4096
#define PIMG 4712         // CBuf image size in floats
#define PSTRF 4720        // image stride in floats (8B aligned)
#define INV6 (1.0f/6.0f)
#define INV24 (1.0f/24.0f)

typedef float v2f __attribute__((ext_vector_type(2)));
typedef unsigned long long u64;
typedef unsigned int u32;

// Signature buffer (LDS and the global partial image share this layout):
//  T4t2 : [ (c*4+eh)*128 + 2*l + p ]  (lane l=(a<<3)|b, e = 2*eh+p)
//  T3b  : [ x*68 + y*8 + z ]   T2: [a*8+b]   T1: [a]
struct __align__(16) CBuf {
    float T4t2[4096];
    float T3b[544];
    float T2[64];
    float T1[8];
};                        // 4712 floats; 4 bufs = 75392 B LDS

// Half-state: wave-half h owns c in [4h, 4h+4).
// S4v[ci*4+eh] = S4[a][b][4h+ci][2eh .. 2eh+1] ; S3[ci] = S3[a][b][4h+ci]
__device__ __forceinline__ void publish_half(CBuf& B, const v2f S4v[16],
                                             const float S3[4], float S2, float a1a,
                                             int l, int a, int b, int h) {
    #pragma unroll
    for (int ci = 0; ci < 4; ++ci)
        #pragma unroll
        for (int eh = 0; eh < 4; ++eh)
            *(v2f*)&B.T4t2[((4*h + ci)*4 + eh)*128 + 2*l] = S4v[ci*4 + eh];
    #pragma unroll
    for (int ci = 0; ci < 4; ++ci)
        B.T3b[a*68 + b*8 + 4*h + ci] = S3[ci];
    if (h == 0) {
        B.T2[l] = S2;
        if (b == 0) B.T1[a] = a1a;
    }
}

__device__ __forceinline__ void absorb_half(const CBuf& B, v2f S4v[16], float S3[4],
                                            float& S2, float& a1a,
                                            int l, int a, int b, int h) {
    v2f t1v[4];
    #pragma unroll
    for (int eh = 0; eh < 4; ++eh) t1v[eh] = *(const v2f*)&B.T1[2*eh];
    const float t1a = B.T1[a], t1b = B.T1[b];
    const v2f S2v = S2, a1v = a1a;
    #pragma unroll
    for (int ci = 0; ci < 4; ++ci) {
        const int c = 4*h + ci;
        const v2f S3cv = S3[ci];
        #pragma unroll
        for (int eh = 0; eh < 4; ++eh) {
            const v2f t2v = *(const v2f*)&B.T2[c*8 + 2*eh];
            const v2f t3v = *(const v2f*)&B.T3b[b*68 + c*8 + 2*eh];
            const v2f t4v = *(const v2f*)&B.T4t2[(c*4 + eh)*128 + 2*l];
            v2f acc = S4v[ci*4 + eh] + t4v;
            acc = __builtin_elementwise_fma(S3cv, t1v[eh], acc);
            acc = __builtin_elementwise_fma(S2v, t2v, acc);
            acc = __builtin_elementwise_fma(a1v, t3v, acc);
            S4v[ci*4 + eh] = acc;
        }
    }
    #pragma unroll
    for (int ci = 0; ci < 4; ++ci) {
        const int c = 4*h + ci;
        S3[ci] += S2 * B.T1[c] + a1a * B.T2[b*8 + c] + B.T3b[a*68 + b*8 + c];
    }
    S2 += a1a * t1b + B.T2[l];
    a1a += t1a;
}

// 64 blocks = 32 batches x 2 halves of 128 segments; 512 threads = 4 wave-pairs.
// Pair pr scans segs [cb*128 + pr*32, +32); 2 intra tree rounds -> pair 0.
// Cross-block: partial stored via agent-scope RELAXED atomic stores (sc1,
// write-through -> no dirty L2, no wbl2/inv fences needed), relaxed flag add;
// second arriver stages peer image and absorbs in fixed (block0 (.) block1)
// order -> deterministic.
__global__ __launch_bounds__(512)
__attribute__((amdgpu_waves_per_eu(2, 2)))
void sig_kernel(const float* __restrict__ path, float* __restrict__ pbase,
                int* __restrict__ flags, float* __restrict__ out) {
    const int blk = blockIdx.x;
    const int n = blk >> 1, cb = blk & 1;
    const int t = threadIdx.x;
    const int w = t >> 6, l = t & 63, a = l >> 3, b = l & 7;
    const int pr = w >> 1, h = w & 1;

    __shared__ CBuf bufs[4];
    __shared__ float dbuf[1024];   // this block's 128 segments x 8
    __shared__ int sh_old;

    const float* prow = path + n * (LPATH*8);
    {
        const int i2 = t * 2;
        const int g2 = cb * 1024 + i2;
        v2f val = {0.f, 0.f};
        if (g2 + 1 < NSEG*8) {          // both elements in segs <= 254
            val.x = prow[g2 + 8] - prow[g2];
            val.y = prow[g2 + 9] - prow[g2 + 1];
        }
        *(v2f*)&dbuf[i2] = val;          // seg 255 -> 0 == identity pad
    }
    __syncthreads();

    v2f S4v[16];
    float S3[4];
    #pragma unroll
    for (int j = 0; j < 16; ++j) S4v[j] = (v2f)0.f;
    #pragma unroll
    for (int ci = 0; ci < 4; ++ci) S3[ci] = 0.f;
    float S2 = 0.f, a1a = 0.f;

    const float* wbase = &dbuf[pr << 8];   // pair's 32 segs * 8 floats
    const float* abase = wbase + a;
    const float* bbase = wbase + b;

    // ---- scan 32 segments, fully unrolled ----
    #pragma unroll
    for (int ss = 0; ss < 32; ++ss) {
        const float4 dlo = *(const float4*)&wbase[ss*8];
        const float4 dhi = *(const float4*)&wbase[ss*8 + 4];
        const v2f dp0 = {dlo.x, dlo.y}, dp1 = {dlo.z, dlo.w};
        const v2f dp2 = {dhi.x, dhi.y}, dp3 = {dhi.z, dhi.w};
        const v2f dcl = h ? dp2 : dp0;    // d[4h+0], d[4h+1]
        const v2f dch = h ? dp3 : dp1;    // d[4h+2], d[4h+3]
        const float da = abase[ss*8];
        const float db = bbase[ss*8];
        const float dab = da * db;
        const float P = dab*INV24 + a1a*db*INV6 + S2*0.5f;
        const float Q = dab*INV6  + a1a*db*0.5f + S2;
        const v2f Pv = P, Qv = Q;
        v2f K0, K1;
        {
            v2f s3l = {S3[0], S3[1]};
            K0 = __builtin_elementwise_fma(dcl, Pv, s3l);
            s3l = __builtin_elementwise_fma(dcl, Qv, s3l);
            S3[0] = s3l.x; S3[1] = s3l.y;
        }
        {
            v2f s3h = {S3[2], S3[3]};
            K1 = __builtin_elementwise_fma(dch, Pv, s3h);
            s3h = __builtin_elementwise_fma(dch, Qv, s3h);
            S3[2] = s3h.x; S3[3] = s3h.y;
        }
        const float Kc[4] = {K0.x, K0.y, K1.x, K1.y};
        #pragma unroll
        for (int ci = 0; ci < 4; ++ci) {
            const v2f Kcv = Kc[ci];
            S4v[ci*4+0] = __builtin_elementwise_fma(dp0, Kcv, S4v[ci*4+0]);
            S4v[ci*4+1] = __builtin_elementwise_fma(dp1, Kcv, S4v[ci*4+1]);
            S4v[ci*4+2] = __builtin_elementwise_fma(dp2, Kcv, S4v[ci*4+2]);
            S4v[ci*4+3] = __builtin_elementwise_fma(dp3, Kcv, S4v[ci*4+3]);
        }
        S2 += db * (da*0.5f + a1a);
        a1a += da;
    }

    // ---- intra-block tree: round 0 (1->0, 3->2), round 1 (2->0) ----
    if (pr & 1) publish_half(bufs[pr >> 1], S4v, S3, S2, a1a, l, a, b, h);
    __syncthreads();
    if (!(pr & 1)) absorb_half(bufs[pr >> 1], S4v, S3, S2, a1a, l, a, b, h);
    __syncthreads();
    if (pr == 2) publish_half(bufs[0], S4v, S3, S2, a1a, l, a, b, h);
    __syncthreads();
    if (pr == 0) absorb_half(bufs[0], S4v, S3, S2, a1a, l, a, b, h);
    __syncthreads();

    // ---- pair 0 stores the partial image via agent-scope relaxed atomics ----
    if (pr == 0) {
        float* p = pbase + (size_t)blk * PSTRF;
        #pragma unroll
        for (int ci = 0; ci < 4; ++ci)
            #pragma unroll
            for (int eh = 0; eh < 4; ++eh) {
                u64 uv; __builtin_memcpy(&uv, &S4v[ci*4 + eh], 8);
                __hip_atomic_store((u64*)&p[((4*h + ci)*4 + eh)*128 + 2*l], uv,
                                   __ATOMIC_RELAXED, __HIP_MEMORY_SCOPE_AGENT);
            }
        #pragma unroll
        for (int ci = 0; ci < 4; ++ci) {
            u32 uv; __builtin_memcpy(&uv, &S3[ci], 4);
            __hip_atomic_store((u32*)&p[4096 + a*68 + b*8 + 4*h + ci], uv,
                               __ATOMIC_RELAXED, __HIP_MEMORY_SCOPE_AGENT);
        }
        if (h == 0) {
            u32 uv; __builtin_memcpy(&uv, &S2, 4);
            __hip_atomic_store((u32*)&p[4640 + l], uv,
                               __ATOMIC_RELAXED, __HIP_MEMORY_SCOPE_AGENT);
            if (b == 0) {
                u32 u1; __builtin_memcpy(&u1, &a1a, 4);
                __hip_atomic_store((u32*)&p[4704 + a], u1,
                                   __ATOMIC_RELAXED, __HIP_MEMORY_SCOPE_AGENT);
            }
        }
        asm volatile("s_waitcnt vmcnt(0)" ::: "memory");  // sc1 stores MALL-visible
    }
    __syncthreads();   // all waves' stores drained before the flag bump
    if (t == 0)
        sh_old = __hip_atomic_fetch_add(&flags[n], 1, __ATOMIC_RELAXED,
                                        __HIP_MEMORY_SCOPE_AGENT);
    __syncthreads();
    if (sh_old != 1) return;          // first arriver exits

    // ---- combiner: stage peer image -> bufs[2] (sc1 loads bypass L2) ----
    {
        const u64* src = (const u64*)(pbase + (size_t)(n*2 + (cb ^ 1)) * PSTRF);
        u64* dst = (u64*)&bufs[2];
        for (int i = t; i < PIMG/2; i += 512)
            dst[i] = __hip_atomic_load(&src[i], __ATOMIC_RELAXED,
                                       __HIP_MEMORY_SCOPE_AGENT);
    }
    __syncthreads();

    if (cb == 1) {
        // we hold the RIGHT operand: publish it, reload LEFT, absorb right
        if (pr == 0) publish_half(bufs[3], S4v, S3, S2, a1a, l, a, b, h);
        __syncthreads();
        if (pr == 0) {
            #pragma unroll
            for (int ci = 0; ci < 4; ++ci)
                #pragma unroll
                for (int eh = 0; eh < 4; ++eh)
                    S4v[ci*4 + eh] =
                        *(const v2f*)&bufs[2].T4t2[((4*h + ci)*4 + eh)*128 + 2*l];
            #pragma unroll
            for (int ci = 0; ci < 4; ++ci)
                S3[ci] = bufs[2].T3b[a*68 + b*8 + 4*h + ci];
            S2 = bufs[2].T2[l];
            a1a = bufs[2].T1[a];
            absorb_half(bufs[3], S4v, S3, S2, a1a, l, a, b, h);
        }
    } else {
        if (pr == 0) absorb_half(bufs[2], S4v, S3, S2, a1a, l, a, b, h);
    }

    // ---- pair 0 writes the final signature ----
    if (pr == 0) {
        float* o = out + n * SIGLEN;
        if (h == 0) {
            if (b == 0) o[a] = a1a;
            o[8 + l] = S2;
        }
        *(float4*)&o[72 + l*8 + 4*h] = make_float4(S3[0], S3[1], S3[2], S3[3]);
        #pragma unroll
        for (int ci = 0; ci < 4; ++ci)
            #pragma unroll
            for (int eh = 0; eh < 4; ++eh)
                *(v2f*)&o[584 + l*64 + (4*h + ci)*8 + 2*eh] = S4v[ci*4 + eh];
    }
}

extern "C" void kernel_launch(void* const* d_in, const int* in_sizes, int n_in,
                              void* d_out, int out_size, void* d_ws, size_t ws_size,
                              hipStream_t stream) {
    const float* path = (const float*)d_in[0];
    float* out = (float*)d_out;
    int* flags = (int*)d_ws;                      // 32 ints
    float* pbase = (float*)d_ws + 256;            // partial images, 1 KB offset
    hipMemsetAsync(d_ws, 0, NBATCH * sizeof(int), stream);
    sig_kernel<<<NBATCH * 2, 512, 0, stream>>>(path, pbase, flags, out);
}